// Round 5
// baseline (90.064 us; speedup 1.0000x reference)
//
#include <hip/hip_runtime.h>
#include <math.h>

#define T_LEN 1024
#define PRED_LEN 256
#define OUT_T (T_LEN + PRED_LEN)
#define DM 256
#define KSEL 32
#define TVC 8

#define TWO_PI_F 6.2831853071795864769f
#define INV1024  0.0009765625f

// pad for layout-B (full 1024 spectrum): break 16- and 256-stride conflicts
#define PAD2(i) ((i) + ((i) >> 4) + ((i) >> 8))

struct cpx { double r, i; };
__device__ __forceinline__ cpx cmul(cpx a, cpx b) {
    return { a.r * b.r - a.i * b.i, a.r * b.i + a.i * b.r };
}

// W16[e] = exp(-2*pi*i*e/16), e = 0..9
__device__ __constant__ double W16R[10] = {
    1.0, 0.9238795325112867561, 0.7071067811865475244, 0.3826834323650897717,
    0.0, -0.3826834323650897717, -0.7071067811865475244, -0.9238795325112867561,
    -1.0, -0.9238795325112867561 };
__device__ __constant__ double W16I[10] = {
    0.0, -0.3826834323650897717, -0.7071067811865475244, -0.9238795325112867561,
    -1.0, -0.9238795325112867561, -0.7071067811865475244, -0.3826834323650897717,
    0.0, 0.3826834323650897717 };

// in-register 16-point DFT: U[k] = sum_n u[n] W16^(n k)
__device__ __forceinline__ void dft16(cpx* u) {
    cpx g[16];
#pragma unroll
    for (int a = 0; a < 4; ++a) {
        cpx x0 = u[a], x1 = u[a + 4], x2 = u[a + 8], x3 = u[a + 12];
        double s02r = x0.r + x2.r, s02i = x0.i + x2.i;
        double d02r = x0.r - x2.r, d02i = x0.i - x2.i;
        double s13r = x1.r + x3.r, s13i = x1.i + x3.i;
        double d13r = x1.r - x3.r, d13i = x1.i - x3.i;
        g[a + 0]  = { s02r + s13r, s02i + s13i };
        g[a + 4]  = { d02r + d13i, d02i - d13r };   // d02 - i*d13
        g[a + 8]  = { s02r - s13r, s02i - s13i };
        g[a + 12] = { d02r - d13i, d02i + d13r };   // d02 + i*d13
    }
#pragma unroll
    for (int k0 = 0; k0 < 4; ++k0) {
        cpx h0 = g[0 + 4 * k0];
        cpx h1 = cmul(g[1 + 4 * k0], { W16R[1 * k0], W16I[1 * k0] });
        cpx h2 = cmul(g[2 + 4 * k0], { W16R[2 * k0], W16I[2 * k0] });
        cpx h3 = cmul(g[3 + 4 * k0], { W16R[3 * k0], W16I[3 * k0] });
        double s02r = h0.r + h2.r, s02i = h0.i + h2.i;
        double d02r = h0.r - h2.r, d02i = h0.i - h2.i;
        double s13r = h1.r + h3.r, s13i = h1.i + h3.i;
        double d13r = h1.r - h3.r, d13i = h1.i - h3.i;
        u[k0 + 0]  = { s02r + s13r, s02i + s13i };
        u[k0 + 4]  = { d02r + d13i, d02i - d13r };
        u[k0 + 8]  = { s02r - s13r, s02i - s13i };
        u[k0 + 12] = { d02r - d13i, d02i + d13r };
    }
}

// ---------------- Kernel T: fp64 twiddle table W[e] = exp(-2pi*i*e/1024) ----------------
__global__ void fl_twiddle_kernel(double* __restrict__ gwr, double* __restrict__ gwi) {
    int e = blockIdx.x * 256 + threadIdx.x;
    double ang = (double)e * (6.283185307179586476925286766559 / 1024.0);
    gwr[e] = cos(ang);
    gwi[e] = -sin(ang);
}

// ---------------- Kernel A: wave-private packed FFT + top-32 ----------------
// grid = 1024 blocks (one column-pair each), block = 64 threads (ONE wave, no barriers)
__global__ void __launch_bounds__(64)
fl_fft_topk_kernel(const float* __restrict__ x,
                   const double* __restrict__ gwr, const double* __restrict__ gwi,
                   int* __restrict__ Mi, float* __restrict__ Ac, float* __restrict__ Bc) {
    __shared__ double reS[1090], imS[1090];

    const int j = threadIdx.x;                       // lane 0..63
    const int bid = blockIdx.x;
    const int sp  = ((bid & 7) << 7) | (bid >> 3);   // XCD-chunked, bijective over 1024
    const int b   = sp >> 7;
    const int d0  = (sp & 127) << 1;

    // ---- P1: lane j owns x[n2=j + 64*n1], n1=0..15 (two real cols packed as complex)
    cpx u[16];
#pragma unroll
    for (int n1 = 0; n1 < 16; ++n1) {
        const float2 v = *reinterpret_cast<const float2*>(
            &x[(((size_t)(b << 10) + j + (n1 << 6)) << 8) + d0]);
        u[n1] = { (double)v.x, (double)v.y };
    }
    dft16(u);
    // twiddle by W1024^(j*k1)
    {
        cpx T = { gwr[j], gwi[j] };
        cpx w = T;
#pragma unroll
        for (int k1 = 1; k1 < 16; ++k1) {
            u[k1] = cmul(u[k1], w);
            w = cmul(w, T);
        }
    }
    // store layout A: idx = k1*65 + j
#pragma unroll
    for (int k1 = 0; k1 < 16; ++k1) {
        reS[k1 * 65 + j] = u[k1].r;
        imS[k1 * 65 + j] = u[k1].i;
    }

    // ---- P2: FFT-64 over n2 for each k1. lane = k1 + 16*rho
    const int k1 = j & 15;
    const int rho = j >> 4;
    cpx a[16];
#pragma unroll
    for (int m = 0; m < 16; ++m) {
        int idx = k1 * 65 + rho + (m << 2);
        a[m] = { reS[idx], imS[idx] };
    }
    dft16(a);
    // twiddle by W64^(rho*kappa1) = (W1024^(16 rho))^kappa1
    {
        cpx T = { gwr[rho << 4], gwi[rho << 4] };
        cpx w = T;
#pragma unroll
        for (int kk = 1; kk < 16; ++kk) {
            a[kk] = cmul(a[kk], w);
            w = cmul(w, T);
        }
    }
    // cross-lane radix-4 over rho (xor32 then xor16), store layout B
    const int k2rho = ((rho & 1) << 1) | (rho >> 1);   // bit-reversed rho
    const bool bit1 = (rho & 2) != 0;
    const bool bit0 = (rho & 1) != 0;
#pragma unroll
    for (int kk = 0; kk < 16; ++kk) {
        cpx A = a[kk];
        double er = __shfl_xor(A.r, 32), ei = __shfl_xor(A.i, 32);
        cpx w1 = bit1 ? cpx{ er - A.r, ei - A.i } : cpx{ A.r + er, A.i + ei };
        double fr = __shfl_xor(w1.r, 16), fi = __shfl_xor(w1.i, 16);
        cpx Y;
        if (!bit1) Y = bit0 ? cpx{ fr - w1.r, fi - w1.i }     // Y2 = S - T
                            : cpx{ w1.r + fr, w1.i + fi };    // Y0 = S + T
        else       Y = bit0 ? cpx{ fr - w1.i, fi + w1.r }     // Y3 = U + i*V
                            : cpx{ w1.r + fi, w1.i - fr };    // Y1 = U - i*V
        int k = k1 + (kk << 4) + (k2rho << 8);
        int pk = PAD2(k);
        reS[pk] = Y.r;
        imS[pk] = Y.i;
    }

    // ---- magnitudes for both packed columns; lane owns m = q*64 + lane
    double v0[8], v1[8];
#pragma unroll
    for (int q = 0; q < 8; ++q) {
        int m = (q << 6) | j;
        int n = (1024 - m) & 1023;
        double rm = reS[PAD2(m)], imv = imS[PAD2(m)];
        double rn = reS[PAD2(n)], inv = imS[PAD2(n)];
        double ar0 = 0.5 * (rm + rn),  ai0 = 0.5 * (imv - inv);
        double ar1 = 0.5 * (imv + inv), ai1 = 0.5 * (rn - rm);
        v0[q] = ar0 * ar0 + ai0 * ai0;
        v1[q] = ar1 * ar1 + ai1 * ai1;
    }
    if (j == 0) { v0[0] = -1.0; v1[0] = -1.0; }   // exclude m=0; m=512 excluded by range

    // ---- top-32 for both columns, interleaved (independent shuffle chains)
    int sel0 = 0, sel1 = 0;
    for (int r = 0; r < KSEL; ++r) {
        double bv0 = v0[0]; int bq0 = 0;
        double bv1 = v1[0]; int bq1 = 0;
#pragma unroll
        for (int q = 1; q < 8; ++q) {
            if (v0[q] > bv0) { bv0 = v0[q]; bq0 = q; }
            if (v1[q] > bv1) { bv1 = v1[q]; bq1 = q; }
        }
        int bi0 = (bq0 << 6) | j;
        int bi1 = (bq1 << 6) | j;
#pragma unroll
        for (int off = 1; off < 64; off <<= 1) {
            double ov0 = __shfl_xor(bv0, off); int oi0 = __shfl_xor(bi0, off);
            double ov1 = __shfl_xor(bv1, off); int oi1 = __shfl_xor(bi1, off);
            if (ov0 > bv0 || (ov0 == bv0 && oi0 < bi0)) { bv0 = ov0; bi0 = oi0; }
            if (ov1 > bv1 || (ov1 == bv1 && oi1 < bi1)) { bv1 = ov1; bi1 = oi1; }
        }
        if (j == r) { sel0 = bi0; sel1 = bi1; }
        if (j == (bi0 & 63)) {
            int wq = bi0 >> 6;
#pragma unroll
            for (int q = 0; q < 8; ++q) if (q == wq) v0[q] = -1.0;
        }
        if (j == (bi1 & 63)) {
            int wq = bi1 >> 6;
#pragma unroll
            for (int q = 0; q < 8; ++q) if (q == wq) v1[q] = -1.0;
        }
    }

    // ---- write coefficients (lanes 0..31 hold round winners)
    if (j < KSEL) {
        const int col0 = (b << 8) + d0;
        {
            int m = sel0, n = (1024 - m) & 1023;
            double rm = reS[PAD2(m)], imv = imS[PAD2(m)];
            double rn = reS[PAD2(n)], inv = imS[PAD2(n)];
            double rr = 0.5 * (rm + rn), ii = 0.5 * (imv - inv);
            int bi_ = col0 * KSEL + j;
            Mi[bi_] = m;
            Ac[bi_] = (float)( rr / 512.0);
            Bc[bi_] = (float)(-ii / 512.0);
        }
        {
            int m = sel1, n = (1024 - m) & 1023;
            double rm = reS[PAD2(m)], imv = imS[PAD2(m)];
            double rn = reS[PAD2(n)], inv = imS[PAD2(n)];
            double rr = 0.5 * (imv + inv), ii = 0.5 * (rn - rm);
            int bi_ = (col0 + 1) * KSEL + j;
            Mi[bi_] = m;
            Ac[bi_] = (float)( rr / 512.0);
            Bc[bi_] = (float)(-ii / 512.0);
        }
    }
}

// ---------------- Kernel B: synthesis (periodic mod 1024, dual-write tail) ----------------
// grid = (1024/TVC, 8), block = 256 (thread = d); no LDS.
__global__ void __launch_bounds__(256)
fl_synth_kernel(const int* __restrict__ Mi, const float* __restrict__ Ac,
                const float* __restrict__ Bc, float* __restrict__ out) {
    const int tid = threadIdx.x;
    const int b   = blockIdx.y;
    const int tv0 = blockIdx.x * TVC;
    const int base = (((b << 8) + tid) << 5);  // (b*256+d)*32

    const int4*   Mi4 = reinterpret_cast<const int4*>(Mi + base);
    const float4* Ac4 = reinterpret_cast<const float4*>(Ac + base);
    const float4* Bc4 = reinterpret_cast<const float4*>(Bc + base);

    float acc[TVC];
#pragma unroll
    for (int i = 0; i < TVC; ++i) acc[i] = 0.0f;

    for (int k8 = 0; k8 < 8; ++k8) {
        int4   m4 = Mi4[k8];
        float4 a4 = Ac4[k8];
        float4 b4 = Bc4[k8];
        int   mm[4] = { m4.x, m4.y, m4.z, m4.w };
        float AA[4] = { a4.x, a4.y, a4.z, a4.w };
        float BB[4] = { b4.x, b4.y, b4.z, b4.w };
        float c[4], s[4], cw[4], sw[4];
#pragma unroll
        for (int u = 0; u < 4; ++u) {
            float f0 = (float)((mm[u] * tv0) & 1023) * INV1024;
            float fw = (float)mm[u] * INV1024;
            c[u]  = __cosf(f0 * TWO_PI_F);
            s[u]  = __sinf(f0 * TWO_PI_F);
            cw[u] = __cosf(fw * TWO_PI_F);
            sw[u] = __sinf(fw * TWO_PI_F);
        }
#pragma unroll
        for (int i = 0; i < TVC; ++i) {
#pragma unroll
            for (int u = 0; u < 4; ++u) {
                acc[i] = fmaf(AA[u], c[u], fmaf(BB[u], s[u], acc[i]));
                float cn = fmaf(c[u], cw[u], -(s[u] * sw[u]));
                float sn = fmaf(s[u], cw[u],  (c[u] * sw[u]));
                c[u] = cn; s[u] = sn;
            }
        }
    }

    float* op = out + ((size_t)b * OUT_T + tv0) * DM + tid;
#pragma unroll
    for (int i = 0; i < TVC; ++i) op[i * DM] = acc[i];

    if (tv0 < PRED_LEN) {   // out[tv+1024] = out[tv] (integer bins -> period 1024)
        float* op2 = out + ((size_t)b * OUT_T + tv0 + T_LEN) * DM + tid;
#pragma unroll
        for (int i = 0; i < TVC; ++i) op2[i * DM] = acc[i];
    }
}

extern "C" void kernel_launch(void* const* d_in, const int* in_sizes, int n_in,
                              void* d_out, int out_size, void* d_ws, size_t ws_size,
                              hipStream_t stream) {
    const float* x = (const float*)d_in[0];
    float* out = (float*)d_out;

    char* w = (char*)d_ws;
    const size_t NSIG = 8 * 256;
    const size_t coefBytes = NSIG * KSEL * sizeof(int);  // 256 KiB each
    int*    Mi  = (int*)(w);
    float*  Ac  = (float*)(w + coefBytes);
    float*  Bc  = (float*)(w + 2 * coefBytes);
    double* gwr = (double*)(w + 3 * coefBytes);
    double* gwi = (double*)(w + 3 * coefBytes + 1024 * sizeof(double));

    hipLaunchKernelGGL(fl_twiddle_kernel, dim3(4), dim3(256), 0, stream, gwr, gwi);
    hipLaunchKernelGGL(fl_fft_topk_kernel, dim3(1024), dim3(64), 0, stream,
                       x, gwr, gwi, Mi, Ac, Bc);
    hipLaunchKernelGGL(fl_synth_kernel, dim3(T_LEN / TVC, 8), dim3(256), 0, stream,
                       Mi, Ac, Bc, out);
}

// Round 6
// 74.047 us; speedup vs baseline: 1.2163x; 1.2163x over previous
//
#include <hip/hip_runtime.h>
#include <math.h>

#define T_LEN 1024
#define PRED_LEN 256
#define OUT_T (T_LEN + PRED_LEN)
#define DM 256
#define KSEL 32
#define TVC 8

#define TWO_PI_F 6.2831853071795864769f
#define INV1024  0.0009765625f

// pad every 32 doubles by 1 to break power-of-2 bank strides
#define SPAD(i) ((i) + ((i) >> 5))

// W16R_[e] = cos(2*pi*e/16), W16I_[e] = -sin(2*pi*e/16)
#define C1_ 0.92387953251128675613
#define C2_ 0.70710678118654752440
#define C3_ 0.38268343236508977173
__device__ __constant__ double W16R_[16] = {
    1.0,  C1_,  C2_,  C3_, 0.0, -C3_, -C2_, -C1_,
   -1.0, -C1_, -C2_, -C3_, 0.0,  C3_,  C2_,  C1_ };
__device__ __constant__ double W16I_[16] = {
    0.0, -C3_, -C2_, -C1_, -1.0, -C1_, -C2_, -C3_,
    0.0,  C3_,  C2_,  C1_,  1.0,  C1_,  C2_,  C3_ };

// ---------------- Kernel T: fp64 twiddle table W[e] = exp(-2pi*i*e/1024) ----------------
__global__ void fl_twiddle_kernel(double* __restrict__ gwr, double* __restrict__ gwi) {
    int e = blockIdx.x * 256 + threadIdx.x;
    double ang = (double)e * (6.283185307179586476925286766559 / 1024.0);
    gwr[e] = cos(ang);
    gwi[e] = -sin(ang);
}

// ---------------- Kernel A: 4-step packed FFT (16x64) + top-32 ----------------
// grid = 1024 blocks (one column-pair each), block = 256 threads = 4 waves.
// wave w, lane = n2; each thread owns k1 = 4w+q outputs of the inner FFT-16,
// then the FFT-64 over n2 runs cross-lane via shuffles (4 independent chains).
__global__ void __launch_bounds__(256, 4)
fl_fft_topk_kernel(const float* __restrict__ x,
                   const double* __restrict__ gwr, const double* __restrict__ gwi,
                   int* __restrict__ Mi, float* __restrict__ Ac, float* __restrict__ Bc) {
    __shared__ double reS[SPAD(1023) + 1], imS[SPAD(1023) + 1];  // gw table, then spectrum
    __shared__ char smemA[8192];   // x as float2[1024], later mg as double[1024]
    float2* xsh = (float2*)smemA;
    double* mg  = (double*)smemA;

    const int tid  = threadIdx.x;
    const int lane = tid & 63;     // = n2
    const int w    = tid >> 6;     // wave 0..3

    const int bid = blockIdx.x;
    const int sp  = ((bid & 7) << 7) | (bid >> 3);   // XCD-chunked, bijective over 1024
    const int b   = sp >> 7;
    const int d0  = (sp & 127) << 1;

    // stage W1024 table (padded) and the packed column-pair into LDS
    for (int j = 0; j < 4; ++j) {
        int e = tid + (j << 8);
        reS[SPAD(e)] = gwr[e];
        imS[SPAD(e)] = gwi[e];
        xsh[e] = *reinterpret_cast<const float2*>(&x[(((size_t)(b << 10) + e) << 8) + d0]);
    }
    __syncthreads();

    // ---- inner FFT-16 outputs C[k1, n2], k1 = 4w+q; 2 passes of 2 q's (VGPR lean)
    double ar[4], ai[4];
#pragma unroll
    for (int pass = 0; pass < 2; ++pass) {
        double Sr[2][4], Si[2][4];
#pragma unroll
        for (int qq = 0; qq < 2; ++qq)
#pragma unroll
            for (int n1a = 0; n1a < 4; ++n1a) { Sr[qq][n1a] = 0.0; Si[qq][n1a] = 0.0; }
#pragma unroll
        for (int n1b = 0; n1b < 4; ++n1b) {
#pragma unroll
            for (int n1a = 0; n1a < 4; ++n1a) {
                float2 xv = xsh[lane + 64 * (n1a + 4 * n1b)];
                double xr = (double)xv.x, xi = (double)xv.y;
#pragma unroll
                for (int qq = 0; qq < 2; ++qq) {
                    const int q = pass * 2 + qq;
                    const int r = (n1b * q) & 3;   // compile-time: rotation by (-i)^r
                    if      (r == 0) { Sr[qq][n1a] += xr; Si[qq][n1a] += xi; }
                    else if (r == 1) { Sr[qq][n1a] += xi; Si[qq][n1a] -= xr; }
                    else if (r == 2) { Sr[qq][n1a] -= xr; Si[qq][n1a] -= xi; }
                    else             { Sr[qq][n1a] -= xi; Si[qq][n1a] += xr; }
                }
            }
        }
#pragma unroll
        for (int qq = 0; qq < 2; ++qq) {
            const int q  = pass * 2 + qq;
            const int k1 = (w << 2) | q;
            double cr = Sr[qq][0], ci = Si[qq][0];
#pragma unroll
            for (int n1a = 1; n1a < 4; ++n1a) {
                int e = (n1a * k1) & 15;           // wave-uniform table index
                double wr = W16R_[e], wi = W16I_[e];
                cr += Sr[qq][n1a] * wr - Si[qq][n1a] * wi;
                ci += Sr[qq][n1a] * wi + Si[qq][n1a] * wr;
            }
            // twiddle W1024^(n2*k1)
            int et = (lane * k1) & 1023;
            double twr = reS[SPAD(et)], twi = imS[SPAD(et)];
            ar[q] = cr * twr - ci * twi;
            ai[q] = cr * twi + ci * twr;
        }
    }

    // ---- FFT-64 over n2, cross-lane DIF, 4 independent chains; twiddle shared
#pragma unroll
    for (int s = 0; s < 6; ++s) {
        const int half = 32 >> s;
        const int e = (lane & (half - 1)) << s;          // < 32
        const double wr = reS[SPAD(e << 4)];             // W64^e = W1024^(16e)
        const double wi = imS[SPAD(e << 4)];
        const bool up = (lane & half) != 0;
#pragma unroll
        for (int q = 0; q < 4; ++q) {
            double orr = __shfl_xor(ar[q], half);
            double oii = __shfl_xor(ai[q], half);
            double sr = ar[q] + orr, si = ai[q] + oii;
            double dr = orr - ar[q], di = oii - ai[q];
            double ur = dr * wr - di * wi;
            double ui = dr * wi + di * wr;
            ar[q] = up ? ur : sr;
            ai[q] = up ? ui : si;
        }
    }
    __syncthreads();   // all gw-table reads done; reS/imS now becomes the spectrum

    {
        const int krev = (int)(__brev((unsigned)lane) >> 26);  // rev6(lane) = k2
#pragma unroll
        for (int q = 0; q < 4; ++q) {
            int k = ((w << 2) | q) + (krev << 4);              // X[k1 + 16*k2]
            reS[SPAD(k)] = ar[q];
            imS[SPAD(k)] = ai[q];
        }
    }
    __syncthreads();

    // ---- magnitudes for both packed columns (conjugate-symmetry unpack)
#pragma unroll
    for (int h = 0; h < 2; ++h) {
        int m = tid + (h << 8);
        int n = (1024 - m) & 1023;
        double rm = reS[SPAD(m)], iv = imS[SPAD(m)];
        double rn = reS[SPAD(n)], in_ = imS[SPAD(n)];
        double rr0 = 0.5 * (rm + rn),  ii0 = 0.5 * (iv - in_);
        double rr1 = 0.5 * (iv + in_), ii1 = 0.5 * (rn - rm);
        mg[m]       = rr0 * rr0 + ii0 * ii0;
        mg[512 + m] = rr1 * rr1 + ii1 * ii1;
    }
    __syncthreads();

    if (tid >= 128) return;        // waves 2,3 done (barrier already passed)
    const int c = tid >> 6;        // column within the pair
    const double* mgc = mg + (c << 9);

    double v[8];
#pragma unroll
    for (int q = 0; q < 8; ++q) v[q] = mgc[(q << 6) | lane];
    if (lane == 0) v[0] = -1.0;    // exclude m=0; m=512 excluded by range

    int mysel = 0;
    for (int r = 0; r < KSEL; ++r) {
        double bv = v[0]; int bq = 0;
#pragma unroll
        for (int q = 1; q < 8; ++q) if (v[q] > bv) { bv = v[q]; bq = q; }
        int bi = (bq << 6) | lane;
#pragma unroll
        for (int off = 1; off < 64; off <<= 1) {
            double ov = __shfl_xor(bv, off);
            int    oi = __shfl_xor(bi, off);
            if (ov > bv || (ov == bv && oi < bi)) { bv = ov; bi = oi; }
        }
        if (lane == r) mysel = bi;
        if (lane == (bi & 63)) {
            int wq = bi >> 6;
#pragma unroll
            for (int q = 0; q < 8; ++q) if (q == wq) v[q] = -1.0;
        }
    }

    if (lane < KSEL) {
        int m = mysel, n = (1024 - m) & 1023;
        double rm = reS[SPAD(m)], iv = imS[SPAD(m)];
        double rn = reS[SPAD(n)], in_ = imS[SPAD(n)];
        double rr, ii;
        if (c == 0) { rr = 0.5 * (rm + rn);  ii = 0.5 * (iv - in_); }
        else        { rr = 0.5 * (iv + in_); ii = 0.5 * (rn - rm); }
        int col   = (b << 8) + d0 + c;
        int basei = col * KSEL + lane;
        Mi[basei] = m;
        Ac[basei] = (float)( rr / 512.0);      //  2*Re/T
        Bc[basei] = (float)(-ii / 512.0);      // -2*Im/T
    }
}

// ---------------- Kernel B: synthesis (periodic mod 1024, dual-write tail) ----------------
// grid = (1024/TVC, 8), block = 256 (thread = d); no LDS.
__global__ void __launch_bounds__(256)
fl_synth_kernel(const int* __restrict__ Mi, const float* __restrict__ Ac,
                const float* __restrict__ Bc, float* __restrict__ out) {
    const int tid = threadIdx.x;
    const int b   = blockIdx.y;
    const int tv0 = blockIdx.x * TVC;
    const int base = (((b << 8) + tid) << 5);  // (b*256+d)*32

    const int4*   Mi4 = reinterpret_cast<const int4*>(Mi + base);
    const float4* Ac4 = reinterpret_cast<const float4*>(Ac + base);
    const float4* Bc4 = reinterpret_cast<const float4*>(Bc + base);

    float acc[TVC];
#pragma unroll
    for (int i = 0; i < TVC; ++i) acc[i] = 0.0f;

    for (int k8 = 0; k8 < 8; ++k8) {
        int4   m4 = Mi4[k8];
        float4 a4 = Ac4[k8];
        float4 b4 = Bc4[k8];
        int   mm[4] = { m4.x, m4.y, m4.z, m4.w };
        float AA[4] = { a4.x, a4.y, a4.z, a4.w };
        float BB[4] = { b4.x, b4.y, b4.z, b4.w };
        float c[4], s[4], cw[4], sw[4];
#pragma unroll
        for (int u = 0; u < 4; ++u) {
            float f0 = (float)((mm[u] * tv0) & 1023) * INV1024;
            float fw = (float)mm[u] * INV1024;
            c[u]  = __cosf(f0 * TWO_PI_F);
            s[u]  = __sinf(f0 * TWO_PI_F);
            cw[u] = __cosf(fw * TWO_PI_F);
            sw[u] = __sinf(fw * TWO_PI_F);
        }
#pragma unroll
        for (int i = 0; i < TVC; ++i) {
#pragma unroll
            for (int u = 0; u < 4; ++u) {
                acc[i] = fmaf(AA[u], c[u], fmaf(BB[u], s[u], acc[i]));
                float cn = fmaf(c[u], cw[u], -(s[u] * sw[u]));
                float sn = fmaf(s[u], cw[u],  (c[u] * sw[u]));
                c[u] = cn; s[u] = sn;
            }
        }
    }

    float* op = out + ((size_t)b * OUT_T + tv0) * DM + tid;
#pragma unroll
    for (int i = 0; i < TVC; ++i) op[i * DM] = acc[i];

    if (tv0 < PRED_LEN) {   // out[tv+1024] = out[tv] (integer bins -> period 1024)
        float* op2 = out + ((size_t)b * OUT_T + tv0 + T_LEN) * DM + tid;
#pragma unroll
        for (int i = 0; i < TVC; ++i) op2[i * DM] = acc[i];
    }
}

extern "C" void kernel_launch(void* const* d_in, const int* in_sizes, int n_in,
                              void* d_out, int out_size, void* d_ws, size_t ws_size,
                              hipStream_t stream) {
    const float* x = (const float*)d_in[0];
    float* out = (float*)d_out;

    char* w = (char*)d_ws;
    const size_t NSIG = 8 * 256;
    const size_t coefBytes = NSIG * KSEL * sizeof(int);  // 256 KiB each
    int*    Mi  = (int*)(w);
    float*  Ac  = (float*)(w + coefBytes);
    float*  Bc  = (float*)(w + 2 * coefBytes);
    double* gwr = (double*)(w + 3 * coefBytes);
    double* gwi = (double*)(w + 3 * coefBytes + 1024 * sizeof(double));

    hipLaunchKernelGGL(fl_twiddle_kernel, dim3(4), dim3(256), 0, stream, gwr, gwi);
    hipLaunchKernelGGL(fl_fft_topk_kernel, dim3(1024), dim3(256), 0, stream,
                       x, gwr, gwi, Mi, Ac, Bc);
    hipLaunchKernelGGL(fl_synth_kernel, dim3(T_LEN / TVC, 8), dim3(256), 0, stream,
                       Mi, Ac, Bc, out);
}

// Round 7
// 60.987 us; speedup vs baseline: 1.4768x; 1.2141x over previous
//
#include <hip/hip_runtime.h>
#include <math.h>

#define T_LEN 1024
#define PRED_LEN 256
#define OUT_T (T_LEN + PRED_LEN)
#define DM 256
#define KSEL 32
#define TVC 8

#define TWO_PI_F 6.2831853071795864769f
#define INV1024  0.0009765625f

// pad every 32 doubles by 1 to break power-of-2 bank strides
#define SPAD(i) ((i) + ((i) >> 5))

// W16R_[e] = cos(2*pi*e/16), W16I_[e] = -sin(2*pi*e/16)
#define C1_ 0.92387953251128675613
#define C2_ 0.70710678118654752440
#define C3_ 0.38268343236508977173
__device__ __constant__ double W16R_[16] = {
    1.0,  C1_,  C2_,  C3_, 0.0, -C3_, -C2_, -C1_,
   -1.0, -C1_, -C2_, -C3_, 0.0,  C3_,  C2_,  C1_ };
__device__ __constant__ double W16I_[16] = {
    0.0, -C3_, -C2_, -C1_, -1.0, -C1_, -C2_, -C3_,
    0.0,  C3_,  C2_,  C1_,  1.0,  C1_,  C2_,  C3_ };

// ---------------- Kernel T: fp64 twiddle table W[e] = exp(-2pi*i*e/1024) ----------------
__global__ void fl_twiddle_kernel(double* __restrict__ gwr, double* __restrict__ gwi) {
    int e = blockIdx.x * 256 + threadIdx.x;
    double ang = (double)e * (6.283185307179586476925286766559 / 1024.0);
    gwr[e] = cos(ang);
    gwi[e] = -sin(ang);
}

// ---------------- Kernel A: 4-step packed FFT (16x64) + histogram top-32 ----------------
// grid = 1024 blocks (one column-pair each), block = 256 threads = 4 waves.
__global__ void __launch_bounds__(256, 4)
fl_fft_topk_kernel(const float* __restrict__ x,
                   const double* __restrict__ gwr, const double* __restrict__ gwi,
                   int* __restrict__ Mi, float* __restrict__ Ac, float* __restrict__ Bc) {
    __shared__ double reS[SPAD(1023) + 1], imS[SPAD(1023) + 1];  // gw table, then spectrum
    __shared__ char smemA[8192];   // x as float2[1024], later mg as double[1024]
    __shared__ int hist[512];      // 256 bins per column
    float2* xsh = (float2*)smemA;
    double* mg  = (double*)smemA;

    const int tid  = threadIdx.x;
    const int lane = tid & 63;     // = n2
    const int w    = tid >> 6;     // wave 0..3

    const int bid = blockIdx.x;
    const int sp  = ((bid & 7) << 7) | (bid >> 3);   // XCD-chunked, bijective over 1024
    const int b   = sp >> 7;
    const int d0  = (sp & 127) << 1;

    // stage W1024 table (padded) and the packed column-pair into LDS
    for (int j = 0; j < 4; ++j) {
        int e = tid + (j << 8);
        reS[SPAD(e)] = gwr[e];
        imS[SPAD(e)] = gwi[e];
        xsh[e] = *reinterpret_cast<const float2*>(&x[(((size_t)(b << 10) + e) << 8) + d0]);
    }
    __syncthreads();

    // ---- inner FFT-16 outputs C[k1, n2], k1 = 4w+q; 2 passes of 2 q's (VGPR lean)
    double ar[4], ai[4];
#pragma unroll
    for (int pass = 0; pass < 2; ++pass) {
        double Sr[2][4], Si[2][4];
#pragma unroll
        for (int qq = 0; qq < 2; ++qq)
#pragma unroll
            for (int n1a = 0; n1a < 4; ++n1a) { Sr[qq][n1a] = 0.0; Si[qq][n1a] = 0.0; }
#pragma unroll
        for (int n1b = 0; n1b < 4; ++n1b) {
#pragma unroll
            for (int n1a = 0; n1a < 4; ++n1a) {
                float2 xv = xsh[lane + 64 * (n1a + 4 * n1b)];
                double xr = (double)xv.x, xi = (double)xv.y;
#pragma unroll
                for (int qq = 0; qq < 2; ++qq) {
                    const int q = pass * 2 + qq;
                    const int r = (n1b * q) & 3;   // compile-time: rotation by (-i)^r
                    if      (r == 0) { Sr[qq][n1a] += xr; Si[qq][n1a] += xi; }
                    else if (r == 1) { Sr[qq][n1a] += xi; Si[qq][n1a] -= xr; }
                    else if (r == 2) { Sr[qq][n1a] -= xr; Si[qq][n1a] -= xi; }
                    else             { Sr[qq][n1a] -= xi; Si[qq][n1a] += xr; }
                }
            }
        }
#pragma unroll
        for (int qq = 0; qq < 2; ++qq) {
            const int q  = pass * 2 + qq;
            const int k1 = (w << 2) | q;
            double cr = Sr[qq][0], ci = Si[qq][0];
#pragma unroll
            for (int n1a = 1; n1a < 4; ++n1a) {
                int e = (n1a * k1) & 15;           // wave-uniform table index
                double wr = W16R_[e], wi = W16I_[e];
                cr += Sr[qq][n1a] * wr - Si[qq][n1a] * wi;
                ci += Sr[qq][n1a] * wi + Si[qq][n1a] * wr;
            }
            // twiddle W1024^(n2*k1)
            int et = (lane * k1) & 1023;
            double twr = reS[SPAD(et)], twi = imS[SPAD(et)];
            ar[q] = cr * twr - ci * twi;
            ai[q] = cr * twi + ci * twr;
        }
    }

    // ---- FFT-64 over n2, cross-lane DIF, 4 independent chains; twiddle shared
#pragma unroll
    for (int s = 0; s < 6; ++s) {
        const int half = 32 >> s;
        const int e = (lane & (half - 1)) << s;          // < 32
        const double wr = reS[SPAD(e << 4)];             // W64^e = W1024^(16e)
        const double wi = imS[SPAD(e << 4)];
        const bool up = (lane & half) != 0;
#pragma unroll
        for (int q = 0; q < 4; ++q) {
            double orr = __shfl_xor(ar[q], half);
            double oii = __shfl_xor(ai[q], half);
            double sr = ar[q] + orr, si = ai[q] + oii;
            double dr = orr - ar[q], di = oii - ai[q];
            double ur = dr * wr - di * wi;
            double ui = dr * wi + di * wr;
            ar[q] = up ? ur : sr;
            ai[q] = up ? ui : si;
        }
    }
    __syncthreads();   // all gw-table reads done; reS/imS now becomes the spectrum

    {
        const int krev = (int)(__brev((unsigned)lane) >> 26);  // rev6(lane) = k2
#pragma unroll
        for (int q = 0; q < 4; ++q) {
            int k = ((w << 2) | q) + (krev << 4);              // X[k1 + 16*k2]
            reS[SPAD(k)] = ar[q];
            imS[SPAD(k)] = ai[q];
        }
    }
    __syncthreads();

    // ---- magnitudes for both packed columns (conjugate-symmetry unpack)
#pragma unroll
    for (int h = 0; h < 2; ++h) {
        int m = tid + (h << 8);
        int n = (1024 - m) & 1023;
        double rm = reS[SPAD(m)], iv = imS[SPAD(m)];
        double rn = reS[SPAD(n)], in_ = imS[SPAD(n)];
        double rr0 = 0.5 * (rm + rn),  ii0 = 0.5 * (iv - in_);
        double rr1 = 0.5 * (iv + in_), ii1 = 0.5 * (rn - rm);
        mg[m]       = rr0 * rr0 + ii0 * ii0;
        mg[512 + m] = rr1 * rr1 + ii1 * ii1;
    }
    __syncthreads();

    if (tid >= 128) return;        // waves 2,3 done (barrier already passed)
    const int c = tid >> 6;        // column within the pair (one wave per column)
    const double* mgc = mg + (c << 9);
    int* histc = hist + (c << 8);

    double v[8]; int hiw[8];
#pragma unroll
    for (int q = 0; q < 8; ++q) v[q] = mgc[(q << 6) | lane];
    if (lane == 0) v[0] = -1.0;    // exclude m=0; m=512 excluded by range
#pragma unroll
    for (int q = 0; q < 8; ++q) hiw[q] = __double2hiint(v[q]);

    // wave-wide max key (positive doubles: hi-word order == numeric order)
    int mx = hiw[0];
#pragma unroll
    for (int q = 1; q < 8; ++q) mx = max(mx, hiw[q]);
#pragma unroll
    for (int off = 1; off < 64; off <<= 1) mx = max(mx, __shfl_xor(mx, off));

    // bin = clamped (hi>>17) window below max: 1/8-octave bins, monotone
    const int base = (mx >> 17) - 250;
    int idx[8];
#pragma unroll
    for (int q = 0; q < 8; ++q) {
        int t = (hiw[q] >> 17) - base;
        idx[q] = t < 0 ? 0 : t;
    }

    // zero own 4 bins, then histogram (same-wave LDS ops are ordered)
    *reinterpret_cast<int4*>(&histc[lane << 2]) = int4{0, 0, 0, 0};
#pragma unroll
    for (int q = 0; q < 8; ++q) atomicAdd(&histc[idx[q]], 1);

    int4 cc = *reinterpret_cast<int4*>(&histc[lane << 2]);
    int s_local = cc.x + cc.y + cc.z + cc.w;

    // inclusive suffix-sum over lanes (lane l gets sum over lanes >= l)
    int s = s_local;
#pragma unroll
    for (int off = 1; off < 64; off <<= 1) {
        int t = __shfl_down(s, off);
        if (lane + off < 64) s += t;
    }
    const int S_gt = s - s_local;          // count in bins of lanes > lane
    // counts strictly above each of my 4 bins (bin 4l+3 is my highest)
    const int A3 = S_gt;
    const int A2 = A3 + cc.w;
    const int A1 = A2 + cc.z;
    const int A0 = A1 + cc.y;

    int foundB = -1, foundR = 0;
    if (A0 < KSEL && A0 + cc.x >= KSEL) { foundB = (lane << 2) | 0; foundR = KSEL - A0; }
    if (A1 < KSEL && A1 + cc.y >= KSEL) { foundB = (lane << 2) | 1; foundR = KSEL - A1; }
    if (A2 < KSEL && A2 + cc.z >= KSEL) { foundB = (lane << 2) | 2; foundR = KSEL - A2; }
    if (A3 < KSEL && A3 + cc.w >= KSEL) { foundB = (lane << 2) | 3; foundR = KSEL - A3; }

    unsigned long long fm = __ballot(foundB >= 0);
    const int src = (int)(__ffsll((unsigned long long)fm) - 1);
    const int B = __shfl(foundB, src);
    const int r = __shfl(foundR, src);

    unsigned selmask = 0, candmask = 0;
#pragma unroll
    for (int q = 0; q < 8; ++q) {
        if (idx[q] > B) selmask |= (1u << q);
        else if (idx[q] == B) candmask |= (1u << q);
    }

    // r rounds of argmax over bin-B candidates only (r is wave-uniform, ~4 expected)
    for (int it = 0; it < r; ++it) {
        double bv = -2.0; int bq = -1;
#pragma unroll
        for (int q = 0; q < 8; ++q) {
            bool cand = ((candmask >> q) & 1u) != 0;
            if (cand && v[q] > bv) { bv = v[q]; bq = q; }
        }
        int bi = (bq < 0) ? 0x7FFFFFFF : ((bq << 6) | lane);
#pragma unroll
        for (int off = 1; off < 64; off <<= 1) {
            double ov = __shfl_xor(bv, off);
            int    oi = __shfl_xor(bi, off);
            if (ov > bv || (ov == bv && oi < bi)) { bv = ov; bi = oi; }
        }
        if (bi != 0x7FFFFFFF && lane == (bi & 63)) {
            unsigned bit = 1u << (bi >> 6);
            selmask  |= bit;
            candmask &= ~bit;
        }
    }

    // exclusive prefix of per-lane selected counts -> output slots (order irrelevant)
    const int cnt = __popc(selmask);
    int p = cnt;
#pragma unroll
    for (int off = 1; off < 64; off <<= 1) {
        int t = __shfl_up(p, off);
        if (lane >= off) p += t;
    }
    int slot = ((((b << 8) + d0 + c) * KSEL)) + (p - cnt);

#pragma unroll
    for (int q = 0; q < 8; ++q) {
        if ((selmask >> q) & 1u) {
            int m = (q << 6) | lane;
            int n = (1024 - m) & 1023;
            double rm = reS[SPAD(m)], iv = imS[SPAD(m)];
            double rn = reS[SPAD(n)], in_ = imS[SPAD(n)];
            double rr, ii;
            if (c == 0) { rr = 0.5 * (rm + rn);  ii = 0.5 * (iv - in_); }
            else        { rr = 0.5 * (iv + in_); ii = 0.5 * (rn - rm); }
            Mi[slot] = m;
            Ac[slot] = (float)( rr / 512.0);      //  2*Re/T
            Bc[slot] = (float)(-ii / 512.0);      // -2*Im/T
            ++slot;
        }
    }
}

// ---------------- Kernel B: synthesis (periodic mod 1024, dual-write tail) ----------------
// grid = (1024/TVC, 8), block = 256 (thread = d); no LDS.
__global__ void __launch_bounds__(256)
fl_synth_kernel(const int* __restrict__ Mi, const float* __restrict__ Ac,
                const float* __restrict__ Bc, float* __restrict__ out) {
    const int tid = threadIdx.x;
    const int b   = blockIdx.y;
    const int tv0 = blockIdx.x * TVC;
    const int base = (((b << 8) + tid) << 5);  // (b*256+d)*32

    const int4*   Mi4 = reinterpret_cast<const int4*>(Mi + base);
    const float4* Ac4 = reinterpret_cast<const float4*>(Ac + base);
    const float4* Bc4 = reinterpret_cast<const float4*>(Bc + base);

    float acc[TVC];
#pragma unroll
    for (int i = 0; i < TVC; ++i) acc[i] = 0.0f;

    for (int k8 = 0; k8 < 8; ++k8) {
        int4   m4 = Mi4[k8];
        float4 a4 = Ac4[k8];
        float4 b4 = Bc4[k8];
        int   mm[4] = { m4.x, m4.y, m4.z, m4.w };
        float AA[4] = { a4.x, a4.y, a4.z, a4.w };
        float BB[4] = { b4.x, b4.y, b4.z, b4.w };
        float c[4], s[4], cw[4], sw[4];
#pragma unroll
        for (int u = 0; u < 4; ++u) {
            float f0 = (float)((mm[u] * tv0) & 1023) * INV1024;
            float fw = (float)mm[u] * INV1024;
            c[u]  = __cosf(f0 * TWO_PI_F);
            s[u]  = __sinf(f0 * TWO_PI_F);
            cw[u] = __cosf(fw * TWO_PI_F);
            sw[u] = __sinf(fw * TWO_PI_F);
        }
#pragma unroll
        for (int i = 0; i < TVC; ++i) {
#pragma unroll
            for (int u = 0; u < 4; ++u) {
                acc[i] = fmaf(AA[u], c[u], fmaf(BB[u], s[u], acc[i]));
                float cn = fmaf(c[u], cw[u], -(s[u] * sw[u]));
                float sn = fmaf(s[u], cw[u],  (c[u] * sw[u]));
                c[u] = cn; s[u] = sn;
            }
        }
    }

    float* op = out + ((size_t)b * OUT_T + tv0) * DM + tid;
#pragma unroll
    for (int i = 0; i < TVC; ++i) op[i * DM] = acc[i];

    if (tv0 < PRED_LEN) {   // out[tv+1024] = out[tv] (integer bins -> period 1024)
        float* op2 = out + ((size_t)b * OUT_T + tv0 + T_LEN) * DM + tid;
#pragma unroll
        for (int i = 0; i < TVC; ++i) op2[i * DM] = acc[i];
    }
}

extern "C" void kernel_launch(void* const* d_in, const int* in_sizes, int n_in,
                              void* d_out, int out_size, void* d_ws, size_t ws_size,
                              hipStream_t stream) {
    const float* x = (const float*)d_in[0];
    float* out = (float*)d_out;

    char* w = (char*)d_ws;
    const size_t NSIG = 8 * 256;
    const size_t coefBytes = NSIG * KSEL * sizeof(int);  // 256 KiB each
    int*    Mi  = (int*)(w);
    float*  Ac  = (float*)(w + coefBytes);
    float*  Bc  = (float*)(w + 2 * coefBytes);
    double* gwr = (double*)(w + 3 * coefBytes);
    double* gwi = (double*)(w + 3 * coefBytes + 1024 * sizeof(double));

    hipLaunchKernelGGL(fl_twiddle_kernel, dim3(4), dim3(256), 0, stream, gwr, gwi);
    hipLaunchKernelGGL(fl_fft_topk_kernel, dim3(1024), dim3(256), 0, stream,
                       x, gwr, gwi, Mi, Ac, Bc);
    hipLaunchKernelGGL(fl_synth_kernel, dim3(T_LEN / TVC, 8), dim3(256), 0, stream,
                       Mi, Ac, Bc, out);
}

// Round 8
// 43.992 us; speedup vs baseline: 2.0473x; 1.3863x over previous
//
#include <hip/hip_runtime.h>
#include <math.h>

#define T_LEN 1024
#define PRED_LEN 256
#define OUT_T (T_LEN + PRED_LEN)
#define DM 256
#define KSEL 32

#define TWO_PI_F 6.2831853071795864769f
#define INV1024  0.0009765625f

// pad every 32 doubles by 1 to break power-of-2 bank strides
#define SPAD(i) ((i) + ((i) >> 5))

// W16R_[e] = cos(2*pi*e/16), W16I_[e] = -sin(2*pi*e/16)
#define C1_ 0.92387953251128675613
#define C2_ 0.70710678118654752440
#define C3_ 0.38268343236508977173
__device__ __constant__ double W16R_[16] = {
    1.0,  C1_,  C2_,  C3_, 0.0, -C3_, -C2_, -C1_,
   -1.0, -C1_, -C2_, -C3_, 0.0,  C3_,  C2_,  C1_ };
__device__ __constant__ double W16I_[16] = {
    0.0, -C3_, -C2_, -C1_, -1.0, -C1_, -C2_, -C3_,
    0.0,  C3_,  C2_,  C1_,  1.0,  C1_,  C2_,  C3_ };

// exact rotation by 2*pi*r/8 (tv stride 128): cos/sin in {0, ±1, ±sqrt2/2}
#define R2_ 0.70710678118654752440f
__device__ __constant__ float CW8[8] = { 1.0f,  R2_, 0.0f, -R2_, -1.0f, -R2_,  0.0f,  R2_ };
__device__ __constant__ float SW8[8] = { 0.0f,  R2_, 1.0f,  R2_,  0.0f, -R2_, -1.0f, -R2_ };

// ---------------- Kernel T: fp64 twiddle table W[e] = exp(-2pi*i*e/1024) ----------------
__global__ void fl_twiddle_kernel(double* __restrict__ gwr, double* __restrict__ gwi) {
    int e = blockIdx.x * 64 + threadIdx.x;
    double ang = (double)e * (6.283185307179586476925286766559 / 1024.0);
    gwr[e] = cos(ang);
    gwi[e] = -sin(ang);
}

// ---------------- Fused kernel: packed FFT (16x64) + histogram top-32 + synthesis ----------------
// grid = 1024 blocks (one column-pair each), block = 256 threads = 4 waves.
__global__ void __launch_bounds__(256, 4)
fl_fused_kernel(const float* __restrict__ x,
                const double* __restrict__ gwr, const double* __restrict__ gwi,
                float* __restrict__ out) {
    __shared__ double reS[SPAD(1023) + 1], imS[SPAD(1023) + 1];  // gw table, then spectrum
    __shared__ char smemA[8192];   // x as float2[1024], later mg as double[1024]
    __shared__ int hist[512];      // 256 bins per column
    __shared__ int   selMs[2 * KSEL];
    __shared__ float selAs[2 * KSEL], selBs[2 * KSEL];
    float2* xsh = (float2*)smemA;
    double* mg  = (double*)smemA;

    const int tid  = threadIdx.x;
    const int lane = tid & 63;     // = n2
    const int w    = tid >> 6;     // wave 0..3

    const int bid = blockIdx.x;
    const int sp  = ((bid & 7) << 7) | (bid >> 3);   // XCD-chunked, bijective over 1024
    const int b   = sp >> 7;
    const int d0  = (sp & 127) << 1;

    // stage W1024 table (padded) and the packed column-pair into LDS
    for (int j = 0; j < 4; ++j) {
        int e = tid + (j << 8);
        reS[SPAD(e)] = gwr[e];
        imS[SPAD(e)] = gwi[e];
        xsh[e] = *reinterpret_cast<const float2*>(&x[(((size_t)(b << 10) + e) << 8) + d0]);
    }
    __syncthreads();

    // ---- inner FFT-16 outputs C[k1, n2], k1 = 4w+q; 2 passes of 2 q's (VGPR lean)
    double ar[4], ai[4];
#pragma unroll
    for (int pass = 0; pass < 2; ++pass) {
        double Sr[2][4], Si[2][4];
#pragma unroll
        for (int qq = 0; qq < 2; ++qq)
#pragma unroll
            for (int n1a = 0; n1a < 4; ++n1a) { Sr[qq][n1a] = 0.0; Si[qq][n1a] = 0.0; }
#pragma unroll
        for (int n1b = 0; n1b < 4; ++n1b) {
#pragma unroll
            for (int n1a = 0; n1a < 4; ++n1a) {
                float2 xv = xsh[lane + 64 * (n1a + 4 * n1b)];
                double xr = (double)xv.x, xi = (double)xv.y;
#pragma unroll
                for (int qq = 0; qq < 2; ++qq) {
                    const int q = pass * 2 + qq;
                    const int r = (n1b * q) & 3;   // compile-time: rotation by (-i)^r
                    if      (r == 0) { Sr[qq][n1a] += xr; Si[qq][n1a] += xi; }
                    else if (r == 1) { Sr[qq][n1a] += xi; Si[qq][n1a] -= xr; }
                    else if (r == 2) { Sr[qq][n1a] -= xr; Si[qq][n1a] -= xi; }
                    else             { Sr[qq][n1a] -= xi; Si[qq][n1a] += xr; }
                }
            }
        }
#pragma unroll
        for (int qq = 0; qq < 2; ++qq) {
            const int q  = pass * 2 + qq;
            const int k1 = (w << 2) | q;
            double cr = Sr[qq][0], ci = Si[qq][0];
#pragma unroll
            for (int n1a = 1; n1a < 4; ++n1a) {
                int e = (n1a * k1) & 15;           // wave-uniform table index
                double wr = W16R_[e], wi = W16I_[e];
                cr += Sr[qq][n1a] * wr - Si[qq][n1a] * wi;
                ci += Sr[qq][n1a] * wi + Si[qq][n1a] * wr;
            }
            // twiddle W1024^(n2*k1)
            int et = (lane * k1) & 1023;
            double twr = reS[SPAD(et)], twi = imS[SPAD(et)];
            ar[q] = cr * twr - ci * twi;
            ai[q] = cr * twi + ci * twr;
        }
    }

    // ---- FFT-64 over n2, cross-lane DIF, 4 independent chains; twiddle shared
#pragma unroll
    for (int s = 0; s < 6; ++s) {
        const int half = 32 >> s;
        const int e = (lane & (half - 1)) << s;          // < 32
        const double wr = reS[SPAD(e << 4)];             // W64^e = W1024^(16e)
        const double wi = imS[SPAD(e << 4)];
        const bool up = (lane & half) != 0;
#pragma unroll
        for (int q = 0; q < 4; ++q) {
            double orr = __shfl_xor(ar[q], half);
            double oii = __shfl_xor(ai[q], half);
            double sr = ar[q] + orr, si = ai[q] + oii;
            double dr = orr - ar[q], di = oii - ai[q];
            double ur = dr * wr - di * wi;
            double ui = dr * wi + di * wr;
            ar[q] = up ? ur : sr;
            ai[q] = up ? ui : si;
        }
    }
    __syncthreads();   // all gw-table reads done; reS/imS now becomes the spectrum

    {
        const int krev = (int)(__brev((unsigned)lane) >> 26);  // rev6(lane) = k2
#pragma unroll
        for (int q = 0; q < 4; ++q) {
            int k = ((w << 2) | q) + (krev << 4);              // X[k1 + 16*k2]
            reS[SPAD(k)] = ar[q];
            imS[SPAD(k)] = ai[q];
        }
    }
    __syncthreads();

    // ---- magnitudes for both packed columns (conjugate-symmetry unpack)
#pragma unroll
    for (int h = 0; h < 2; ++h) {
        int m = tid + (h << 8);
        int n = (1024 - m) & 1023;
        double rm = reS[SPAD(m)], iv = imS[SPAD(m)];
        double rn = reS[SPAD(n)], in_ = imS[SPAD(n)];
        double rr0 = 0.5 * (rm + rn),  ii0 = 0.5 * (iv - in_);
        double rr1 = 0.5 * (iv + in_), ii1 = 0.5 * (rn - rm);
        mg[m]       = rr0 * rr0 + ii0 * ii0;
        mg[512 + m] = rr1 * rr1 + ii1 * ii1;
    }
    __syncthreads();

    // ---- histogram top-32 (waves 0,1: one wave per column), coefs -> LDS
    if (tid < 128) {
        const int c = tid >> 6;
        const double* mgc = mg + (c << 9);
        int* histc = hist + (c << 8);

        double v[8]; int hiw[8];
#pragma unroll
        for (int q = 0; q < 8; ++q) v[q] = mgc[(q << 6) | lane];
        if (lane == 0) v[0] = -1.0;    // exclude m=0; m=512 excluded by range
#pragma unroll
        for (int q = 0; q < 8; ++q) hiw[q] = __double2hiint(v[q]);

        int mx = hiw[0];
#pragma unroll
        for (int q = 1; q < 8; ++q) mx = max(mx, hiw[q]);
#pragma unroll
        for (int off = 1; off < 64; off <<= 1) mx = max(mx, __shfl_xor(mx, off));

        const int base = (mx >> 17) - 250;
        int idx[8];
#pragma unroll
        for (int q = 0; q < 8; ++q) {
            int t = (hiw[q] >> 17) - base;
            idx[q] = t < 0 ? 0 : t;
        }

        *reinterpret_cast<int4*>(&histc[lane << 2]) = int4{0, 0, 0, 0};
#pragma unroll
        for (int q = 0; q < 8; ++q) atomicAdd(&histc[idx[q]], 1);

        int4 cc = *reinterpret_cast<int4*>(&histc[lane << 2]);
        int s_local = cc.x + cc.y + cc.z + cc.w;

        int s = s_local;
#pragma unroll
        for (int off = 1; off < 64; off <<= 1) {
            int t = __shfl_down(s, off);
            if (lane + off < 64) s += t;
        }
        const int S_gt = s - s_local;
        const int A3 = S_gt;
        const int A2 = A3 + cc.w;
        const int A1 = A2 + cc.z;
        const int A0 = A1 + cc.y;

        int foundB = -1, foundR = 0;
        if (A0 < KSEL && A0 + cc.x >= KSEL) { foundB = (lane << 2) | 0; foundR = KSEL - A0; }
        if (A1 < KSEL && A1 + cc.y >= KSEL) { foundB = (lane << 2) | 1; foundR = KSEL - A1; }
        if (A2 < KSEL && A2 + cc.z >= KSEL) { foundB = (lane << 2) | 2; foundR = KSEL - A2; }
        if (A3 < KSEL && A3 + cc.w >= KSEL) { foundB = (lane << 2) | 3; foundR = KSEL - A3; }

        unsigned long long fm = __ballot(foundB >= 0);
        const int src = (int)(__ffsll((unsigned long long)fm) - 1);
        const int B = __shfl(foundB, src);
        const int r = __shfl(foundR, src);

        unsigned selmask = 0, candmask = 0;
#pragma unroll
        for (int q = 0; q < 8; ++q) {
            if (idx[q] > B) selmask |= (1u << q);
            else if (idx[q] == B) candmask |= (1u << q);
        }

        for (int it = 0; it < r; ++it) {
            double bv = -2.0; int bq = -1;
#pragma unroll
            for (int q = 0; q < 8; ++q) {
                bool cand = ((candmask >> q) & 1u) != 0;
                if (cand && v[q] > bv) { bv = v[q]; bq = q; }
            }
            int bi = (bq < 0) ? 0x7FFFFFFF : ((bq << 6) | lane);
#pragma unroll
            for (int off = 1; off < 64; off <<= 1) {
                double ov = __shfl_xor(bv, off);
                int    oi = __shfl_xor(bi, off);
                if (ov > bv || (ov == bv && oi < bi)) { bv = ov; bi = oi; }
            }
            if (bi != 0x7FFFFFFF && lane == (bi & 63)) {
                unsigned bit = 1u << (bi >> 6);
                selmask  |= bit;
                candmask &= ~bit;
            }
        }

        const int cnt = __popc(selmask);
        int p = cnt;
#pragma unroll
        for (int off = 1; off < 64; off <<= 1) {
            int t = __shfl_up(p, off);
            if (lane >= off) p += t;
        }
        int slot = (c << 5) + (p - cnt);

#pragma unroll
        for (int q = 0; q < 8; ++q) {
            if ((selmask >> q) & 1u) {
                int m = (q << 6) | lane;
                int n = (1024 - m) & 1023;
                double rm = reS[SPAD(m)], iv = imS[SPAD(m)];
                double rn = reS[SPAD(n)], in_ = imS[SPAD(n)];
                double rr, ii;
                if (c == 0) { rr = 0.5 * (rm + rn);  ii = 0.5 * (iv - in_); }
                else        { rr = 0.5 * (iv + in_); ii = 0.5 * (rn - rm); }
                selMs[slot] = m;
                selAs[slot] = (float)( rr / 512.0);      //  2*Re/T
                selBs[slot] = (float)(-ii / 512.0);      // -2*Im/T
                ++slot;
            }
        }
    }
    __syncthreads();

    // ---- synthesis: thread = (col = tid&1, j = tid>>1); tv = j + 128*q_
    {
        const int col = tid & 1;
        const int j   = tid >> 1;          // 0..127
        float acc[10];
#pragma unroll
        for (int i = 0; i < 10; ++i) acc[i] = 0.0f;

        const int cbase = col << 5;
        for (int k = 0; k < KSEL; ++k) {
            const int   m = selMs[cbase + k];
            const float A = selAs[cbase + k];
            const float B = selBs[cbase + k];
            const int   r = m & 7;
            const float cw = CW8[r], sw = SW8[r];
            const float th = (float)((m * j) & 1023) * (INV1024 * TWO_PI_F);
            float cs = __cosf(th);
            float sn = __sinf(th);
#pragma unroll
            for (int i = 0; i < 10; ++i) {
                acc[i] = fmaf(A, cs, fmaf(B, sn, acc[i]));
                float cn = fmaf(cs, cw, -(sn * sw));
                float s2 = fmaf(sn, cw,  (cs * sw));
                cs = cn; sn = s2;
            }
        }

        float* op = out + ((size_t)b * OUT_T + j) * DM + d0 + col;
#pragma unroll
        for (int i = 0; i < 10; ++i) {
            op[(size_t)i * 128 * DM] = acc[i];
        }
    }
}

extern "C" void kernel_launch(void* const* d_in, const int* in_sizes, int n_in,
                              void* d_out, int out_size, void* d_ws, size_t ws_size,
                              hipStream_t stream) {
    const float* x = (const float*)d_in[0];
    float* out = (float*)d_out;

    char* w = (char*)d_ws;
    double* gwr = (double*)(w);
    double* gwi = (double*)(w + 1024 * sizeof(double));

    hipLaunchKernelGGL(fl_twiddle_kernel, dim3(16), dim3(64), 0, stream, gwr, gwi);
    hipLaunchKernelGGL(fl_fused_kernel, dim3(1024), dim3(256), 0, stream,
                       x, gwr, gwi, out);
}

// Round 9
// 41.817 us; speedup vs baseline: 2.1537x; 1.0520x over previous
//
#include <hip/hip_runtime.h>
#include <math.h>

#define T_LEN 1024
#define PRED_LEN 256
#define OUT_T (T_LEN + PRED_LEN)
#define DM 256
#define KSEL 32

#define TWO_PI_F 6.2831853071795864769f
#define INV1024  0.0009765625f
#define RTAU 1e-4f

// pad every 32 floats by 1 to break power-of-2 bank strides
#define SPAD(i) ((i) + ((i) >> 5))

// W16[e] = exp(-2*pi*i*e/16), fp32
__device__ __constant__ float W16RF[16] = {
    1.0f,  0.92387953f,  0.70710678f,  0.38268343f, 0.0f, -0.38268343f, -0.70710678f, -0.92387953f,
   -1.0f, -0.92387953f, -0.70710678f, -0.38268343f, 0.0f,  0.38268343f,  0.70710678f,  0.92387953f };
__device__ __constant__ float W16IF[16] = {
    0.0f, -0.38268343f, -0.70710678f, -0.92387953f, -1.0f, -0.92387953f, -0.70710678f, -0.38268343f,
    0.0f,  0.38268343f,  0.70710678f,  0.92387953f,  1.0f,  0.92387953f,  0.70710678f,  0.38268343f };

// exact rotation by 2*pi*r/8 (tv stride 128)
#define R2_ 0.70710678118654752440f
__device__ __constant__ float CW8[8] = { 1.0f,  R2_, 0.0f, -R2_, -1.0f, -R2_,  0.0f,  R2_ };
__device__ __constant__ float SW8[8] = { 0.0f,  R2_, 1.0f,  R2_,  0.0f, -R2_, -1.0f, -R2_ };

// ---------------- Kernel T: twiddle tables W[e] = exp(-2pi*i*e/1024), fp64 + fp32 ----------------
__global__ void fl_twiddle_kernel(double* __restrict__ gwr, double* __restrict__ gwi,
                                  float* __restrict__ gwrF, float* __restrict__ gwiF) {
    int e = blockIdx.x * 64 + threadIdx.x;
    double ang = (double)e * (6.283185307179586476925286766559 / 1024.0);
    double c = cos(ang), s = -sin(ang);
    gwr[e] = c; gwi[e] = s;
    gwrF[e] = (float)c; gwiF[e] = (float)s;
}

// ---------------- Fused: fp32 packed FFT (16x64) + hist top-32 + fp64 boundary refine + synthesis ----------------
// grid = 1024 blocks (one column-pair each), block = 256 threads = 4 waves.
__global__ void __launch_bounds__(256, 4)
fl_fused_kernel(const float* __restrict__ x,
                const double* __restrict__ gwr, const double* __restrict__ gwi,
                const float* __restrict__ gwrF, const float* __restrict__ gwiF,
                float* __restrict__ out) {
    __shared__ float gspR[SPAD(1023) + 1], gspI[SPAD(1023) + 1];  // fp32 twiddles, then spectrum
    __shared__ float2 xsh[1024];     // input pair; PERSISTS (used by fp64 refinement)
    __shared__ float mg[1024];       // |X|^2 for both columns
    __shared__ int hist[512];
    __shared__ int   selMs[2 * KSEL];
    __shared__ float selAs[2 * KSEL], selBs[2 * KSEL];

    const int tid  = threadIdx.x;
    const int lane = tid & 63;       // = n2
    const int w    = tid >> 6;       // wave 0..3

    const int bid = blockIdx.x;
    const int sp  = ((bid & 7) << 7) | (bid >> 3);   // XCD-chunked, bijective over 1024
    const int b   = sp >> 7;
    const int d0  = (sp & 127) << 1;

    // stage fp32 twiddles (padded) and the packed column-pair into LDS
    for (int j = 0; j < 4; ++j) {
        int e = tid + (j << 8);
        gspR[SPAD(e)] = gwrF[e];
        gspI[SPAD(e)] = gwiF[e];
        xsh[e] = *reinterpret_cast<const float2*>(&x[(((size_t)(b << 10) + e) << 8) + d0]);
    }
    __syncthreads();

    // ---- FFT-16 over n1 (fp32): shared DFT-4 partials, then 4 outputs k1 = 4w+q
    float Fr[4][4], Fi[4][4];        // F[n1a][f]
#pragma unroll
    for (int n1a = 0; n1a < 4; ++n1a) {
        float2 a  = xsh[lane + 64 * (n1a + 0)];
        float2 bb = xsh[lane + 64 * (n1a + 4)];
        float2 cV = xsh[lane + 64 * (n1a + 8)];
        float2 d  = xsh[lane + 64 * (n1a + 12)];
        float t0r = a.x + cV.x, t0i = a.y + cV.y;
        float t1r = a.x - cV.x, t1i = a.y - cV.y;
        float t2r = bb.x + d.x, t2i = bb.y + d.y;
        float t3r = bb.x - d.x, t3i = bb.y - d.y;
        Fr[n1a][0] = t0r + t2r;  Fi[n1a][0] = t0i + t2i;
        Fr[n1a][2] = t0r - t2r;  Fi[n1a][2] = t0i - t2i;
        Fr[n1a][1] = t1r + t3i;  Fi[n1a][1] = t1i - t3r;   // t1 - i*t3
        Fr[n1a][3] = t1r - t3i;  Fi[n1a][3] = t1i + t3r;   // t1 + i*t3
    }

    float ar[4], ai[4];
#pragma unroll
    for (int q = 0; q < 4; ++q) {
        const int k1 = (w << 2) | q;
        float cr = Fr[0][q], ci = Fi[0][q];
#pragma unroll
        for (int n1a = 1; n1a < 4; ++n1a) {
            int e = (n1a * k1) & 15;
            float wr = W16RF[e], wi = W16IF[e];
            cr += Fr[n1a][q] * wr - Fi[n1a][q] * wi;
            ci += Fr[n1a][q] * wi + Fi[n1a][q] * wr;
        }
        int et = (lane * k1) & 1023;
        float twr = gspR[SPAD(et)], twi = gspI[SPAD(et)];
        ar[q] = cr * twr - ci * twi;
        ai[q] = cr * twi + ci * twr;
    }

    // ---- FFT-64 over n2, cross-lane DIF (fp32 shfl), 4 independent chains
#pragma unroll
    for (int s = 0; s < 6; ++s) {
        const int half = 32 >> s;
        const int e = (lane & (half - 1)) << s;
        const float wr = gspR[SPAD(e << 4)];   // W64^e = W1024^(16e)
        const float wi = gspI[SPAD(e << 4)];
        const bool up = (lane & half) != 0;
#pragma unroll
        for (int q = 0; q < 4; ++q) {
            float orr = __shfl_xor(ar[q], half);
            float oii = __shfl_xor(ai[q], half);
            float sr = ar[q] + orr, si = ai[q] + oii;
            float dr = orr - ar[q], di = oii - ai[q];
            float ur = dr * wr - di * wi;
            float ui = dr * wi + di * wr;
            ar[q] = up ? ur : sr;
            ai[q] = up ? ui : si;
        }
    }
    __syncthreads();   // all twiddle-table reads done; gspR/gspI becomes the spectrum

    {
        const int krev = (int)(__brev((unsigned)lane) >> 26);  // rev6(lane) = k2
#pragma unroll
        for (int q = 0; q < 4; ++q) {
            int k = ((w << 2) | q) + (krev << 4);              // X[k1 + 16*k2]
            gspR[SPAD(k)] = ar[q];
            gspI[SPAD(k)] = ai[q];
        }
    }
    __syncthreads();

    // ---- magnitudes for both packed columns (conjugate-symmetry unpack)
#pragma unroll
    for (int h = 0; h < 2; ++h) {
        int m = tid + (h << 8);
        int n = (1024 - m) & 1023;
        float rm = gspR[SPAD(m)], iv = gspI[SPAD(m)];
        float rn = gspR[SPAD(n)], in_ = gspI[SPAD(n)];
        float rr0 = 0.5f * (rm + rn),  ii0 = 0.5f * (iv - in_);
        float rr1 = 0.5f * (iv + in_), ii1 = 0.5f * (rn - rm);
        mg[m]       = rr0 * rr0 + ii0 * ii0;
        mg[512 + m] = rr1 * rr1 + ii1 * ii1;
    }
    __syncthreads();

    // ---- histogram top-32 (waves 0,1: one wave per column) + fp64 boundary refinement
    if (tid < 128) {
        const int c = tid >> 6;
        const float* mgc = mg + (c << 9);
        int* histc = hist + (c << 8);

        float v[8]; int hiw[8];
#pragma unroll
        for (int q = 0; q < 8; ++q) v[q] = mgc[(q << 6) | lane];
        if (lane == 0) v[0] = -1.0f;   // exclude m=0; m=512 excluded by range
#pragma unroll
        for (int q = 0; q < 8; ++q) hiw[q] = __float_as_int(v[q]);

        int mx = hiw[0];
#pragma unroll
        for (int q = 1; q < 8; ++q) mx = max(mx, hiw[q]);
#pragma unroll
        for (int off = 1; off < 64; off <<= 1) mx = max(mx, __shfl_xor(mx, off));

        const int base = (mx >> 20) - 250;
        int idx[8];
#pragma unroll
        for (int q = 0; q < 8; ++q) {
            int t = (hiw[q] >> 20) - base;
            idx[q] = t < 0 ? 0 : t;
        }

        *reinterpret_cast<int4*>(&histc[lane << 2]) = int4{0, 0, 0, 0};
#pragma unroll
        for (int q = 0; q < 8; ++q) atomicAdd(&histc[idx[q]], 1);

        int4 cc = *reinterpret_cast<int4*>(&histc[lane << 2]);
        int s_local = cc.x + cc.y + cc.z + cc.w;

        int s = s_local;
#pragma unroll
        for (int off = 1; off < 64; off <<= 1) {
            int t = __shfl_down(s, off);
            if (lane + off < 64) s += t;
        }
        const int S_gt = s - s_local;
        const int A3 = S_gt;
        const int A2 = A3 + cc.w;
        const int A1 = A2 + cc.z;
        const int A0 = A1 + cc.y;

        int foundB = -1, foundR = 0;
        if (A0 < KSEL && A0 + cc.x >= KSEL) { foundB = (lane << 2) | 0; foundR = KSEL - A0; }
        if (A1 < KSEL && A1 + cc.y >= KSEL) { foundB = (lane << 2) | 1; foundR = KSEL - A1; }
        if (A2 < KSEL && A2 + cc.z >= KSEL) { foundB = (lane << 2) | 2; foundR = KSEL - A2; }
        if (A3 < KSEL && A3 + cc.w >= KSEL) { foundB = (lane << 2) | 3; foundR = KSEL - A3; }

        unsigned long long fm = __ballot(foundB >= 0);
        const int srcB = (int)(__ffsll((unsigned long long)fm) - 1);
        const int B = __shfl(foundB, srcB);
        const int r = __shfl(foundR, srcB);

        unsigned selmask = 0, candmask = 0;
#pragma unroll
        for (int q = 0; q < 8; ++q) {
            if (idx[q] > B) selmask |= (1u << q);
            else if (idx[q] == B) candmask |= (1u << q);
        }

        for (int it = 0; it < r; ++it) {
            float bv = -2.0f; int bq = -1;
#pragma unroll
            for (int q = 0; q < 8; ++q) {
                bool cand = ((candmask >> q) & 1u) != 0;
                if (cand && v[q] > bv) { bv = v[q]; bq = q; }
            }
            int bi = (bq < 0) ? 0x7FFFFFFF : ((bq << 6) | lane);
#pragma unroll
            for (int off = 1; off < 64; off <<= 1) {
                float ov = __shfl_xor(bv, off);
                int   oi = __shfl_xor(bi, off);
                if (ov > bv || (ov == bv && oi < bi)) { bv = ov; bi = oi; }
            }
            if (bi != 0x7FFFFFFF && lane == (bi & 63)) {
                unsigned bit = 1u << (bi >> 6);
                selmask  |= bit;
                candmask &= ~bit;
            }
        }

        // ---- fp64 refinement when the rank-32/33 fp32 gap is too small
        {
            float vminS = 3.0e38f, vmaxU = -3.0e38f;
#pragma unroll
            for (int q = 0; q < 8; ++q) {
                if ((selmask >> q) & 1u) vminS = fminf(vminS, v[q]);
                else                     vmaxU = fmaxf(vmaxU, v[q]);
            }
#pragma unroll
            for (int off = 1; off < 64; off <<= 1) {
                vminS = fminf(vminS, __shfl_xor(vminS, off));
                vmaxU = fmaxf(vmaxU, __shfl_xor(vmaxU, off));
            }
            const float tau = RTAU * vminS;
            if (vminS - vmaxU < tau) {            // wave-uniform
                const float lo = vmaxU - tau, hi = vminS + tau;
                unsigned candq = 0; int nAbove = 0;
#pragma unroll
                for (int q = 0; q < 8; ++q) {
                    bool inw = (v[q] >= lo) && (v[q] <= hi);
                    if (inw) candq |= (1u << q);
                    if (((selmask >> q) & 1u) && v[q] > hi) ++nAbove;
                }
#pragma unroll
                for (int off = 1; off < 64; off <<= 1) nAbove += __shfl_xor(nAbove, off);
                const int kneed = KSEL - nAbove;
                selmask &= ~candq;                 // drop window members; re-pick in fp64

                double sV = -1.0; int sSrc = 0; int cnum = 0;
                for (int q = 0; q < 8; ++q) {
                    unsigned long long bal = __ballot((candq >> q) & 1u);
                    while (bal) {
                        int srcl = (int)(__ffsll(bal) - 1);
                        bal &= bal - 1;
                        int m = (q << 6) | srcl;
                        // cooperative exact fp64 DFT bin m of real column c
                        double sr = 0.0, si = 0.0;
                        for (int u = 0; u < 16; ++u) {
                            int n = lane + (u << 6);
                            float2 xv2 = xsh[n];
                            double xvd = (double)(c ? xv2.y : xv2.x);
                            int e = (m * n) & 1023;
                            sr = fma(xvd, gwr[e], sr);
                            si = fma(xvd, gwi[e], si);
                        }
#pragma unroll
                        for (int off = 1; off < 64; off <<= 1) {
                            sr += __shfl_xor(sr, off);
                            si += __shfl_xor(si, off);
                        }
                        if (lane == cnum) { sV = sr * sr + si * si; sSrc = (q << 6) | srcl; }
                        ++cnum;
                        if (cnum >= 64) break;
                    }
                    if (cnum >= 64) break;
                }
                for (int it = 0; it < kneed; ++it) {
                    double bv = sV; int bl = lane;
#pragma unroll
                    for (int off = 1; off < 64; off <<= 1) {
                        double ov = __shfl_xor(bv, off);
                        int    ol = __shfl_xor(bl, off);
                        if (ov > bv || (ov == bv && ol < bl)) { bv = ov; bl = ol; }
                    }
                    int wsrc = __shfl(sSrc, bl);
                    if (lane == (wsrc & 63)) selmask |= 1u << (wsrc >> 6);
                    if (lane == bl) sV = -2.0;
                }
            }
        }

        const int cnt = __popc(selmask);
        int p = cnt;
#pragma unroll
        for (int off = 1; off < 64; off <<= 1) {
            int t = __shfl_up(p, off);
            if (lane >= off) p += t;
        }
        int slot = (c << 5) + (p - cnt);

#pragma unroll
        for (int q = 0; q < 8; ++q) {
            if ((selmask >> q) & 1u) {
                int m = (q << 6) | lane;
                int n = (1024 - m) & 1023;
                float rm = gspR[SPAD(m)], iv = gspI[SPAD(m)];
                float rn = gspR[SPAD(n)], in_ = gspI[SPAD(n)];
                float rr, ii;
                if (c == 0) { rr = 0.5f * (rm + rn);  ii = 0.5f * (iv - in_); }
                else        { rr = 0.5f * (iv + in_); ii = 0.5f * (rn - rm); }
                selMs[slot] = m;
                selAs[slot] = rr * (1.0f / 512.0f);      //  2*Re/T
                selBs[slot] = -ii * (1.0f / 512.0f);     // -2*Im/T
                ++slot;
            }
        }
    }
    __syncthreads();

    // ---- synthesis: thread = (col = tid&1, j = tid>>1); tv = j + 128*i
    {
        const int col = tid & 1;
        const int j   = tid >> 1;          // 0..127
        float acc[10];
#pragma unroll
        for (int i = 0; i < 10; ++i) acc[i] = 0.0f;

        const int cbase = col << 5;
        for (int k = 0; k < KSEL; ++k) {
            const int   m = selMs[cbase + k];
            const float A = selAs[cbase + k];
            const float B = selBs[cbase + k];
            const int   rr8 = m & 7;
            const float cw = CW8[rr8], sw = SW8[rr8];
            const float th = (float)((m * j) & 1023) * (INV1024 * TWO_PI_F);
            float cs = __cosf(th);
            float sn = __sinf(th);
#pragma unroll
            for (int i = 0; i < 10; ++i) {
                acc[i] = fmaf(A, cs, fmaf(B, sn, acc[i]));
                float cn = fmaf(cs, cw, -(sn * sw));
                float s2 = fmaf(sn, cw,  (cs * sw));
                cs = cn; sn = s2;
            }
        }

        float* op = out + ((size_t)b * OUT_T + j) * DM + d0 + col;
#pragma unroll
        for (int i = 0; i < 10; ++i) {
            op[(size_t)i * 128 * DM] = acc[i];
        }
    }
}

extern "C" void kernel_launch(void* const* d_in, const int* in_sizes, int n_in,
                              void* d_out, int out_size, void* d_ws, size_t ws_size,
                              hipStream_t stream) {
    const float* x = (const float*)d_in[0];
    float* out = (float*)d_out;

    char* w = (char*)d_ws;
    double* gwr  = (double*)(w);
    double* gwi  = (double*)(w + 1024 * sizeof(double));
    float*  gwrF = (float*)(w + 2048 * sizeof(double));
    float*  gwiF = (float*)(w + 2048 * sizeof(double) + 1024 * sizeof(float));

    hipLaunchKernelGGL(fl_twiddle_kernel, dim3(16), dim3(64), 0, stream, gwr, gwi, gwrF, gwiF);
    hipLaunchKernelGGL(fl_fused_kernel, dim3(1024), dim3(256), 0, stream,
                       x, gwr, gwi, gwrF, gwiF, out);
}